// Round 1
// baseline (60.305 us; speedup 1.0000x reference)
//
#include <hip/hip_runtime.h>

// SuperResolve: A=4 frames, n=4, c=3, h=w=256, S=2 -> out (4,3,512,512) fp32
// One thread per output pixel (n,y,x); computes all 3 channels.

#define SCALE   2
#define RADIUS  4.0f
#define AF      4      // alternate frames
#define NB      4      // batch
#define CH      3      // channels
#define H       256
#define W       256
#define SH      512
#define SW      512

__global__ __launch_bounds__(256) void superresolve_kernel(
    const float* __restrict__ alts,     // [AF][NB][CH][H][W]
    const float* __restrict__ offsets,  // [AF][NB][2][H][W]
    const float* __restrict__ qs,       // [AF][NB][H][W]
    const float* __restrict__ o11,      // [NB][SH][SW]
    const float* __restrict__ o12,
    const float* __restrict__ o21,
    const float* __restrict__ o22,
    float* __restrict__ out)            // [NB][CH][SH][SW]
{
    const int idx = blockIdx.x * blockDim.x + threadIdx.x;
    // idx = (nn*SH + y)*SW + x
    const int x  = idx & (SW - 1);
    const int y  = (idx >> 9) & (SH - 1);
    const int nn = idx >> 18;

    const int y0 = y >> 1;
    const int x0 = x >> 1;
    const float yf = (float)y;
    const float xf = (float)x;

    const int oidx = (nn * SH + y) * SW + x;
    const float m11  = o11[oidx];
    const float m12s = o12[oidx] + o21[oidx];
    const float m22  = o22[oidx];

    float sumw = 0.0f, s0 = 0.0f, s1 = 0.0f, s2 = 0.0f;

    #pragma unroll
    for (int a = 0; a < AF; ++a) {
        const float* offb = offsets + (size_t)(a * NB + nn) * 2 * (H * W);
        const float* qb   = qs      + (size_t)(a * NB + nn) * (H * W);
        const float* altb = alts    + (size_t)(a * NB + nn) * CH * (H * W);
        #pragma unroll
        for (int k = 0; k < 9; ++k) {
            const int di = k / 3 - 1;
            const int dj = k % 3 - 1;
            const int rn = y0 + di;
            const int cn = x0 + dj;
            if (rn < 0 || rn >= H || cn < 0 || cn >= W) continue;   // inb mask: zero weight in ref
            const int lidx = rn * W + cn;

            const float offr = offb[lidx];
            const float offc = offb[H * W + lidx];
            const float posr = (float)(rn * SCALE) + offr * (float)SCALE;
            const float posc = (float)(cn * SCALE) + offc * (float)SCALE;
            const float dyS = posr - yf;
            const float dxS = posc - xf;
            if (fabsf(dyS) > RADIUS || fabsf(dxS) > RADIUS) continue; // radius mask
            const float dy = dyS * 0.5f;
            const float dx = dxS * 0.5f;
            float dist = dx * dx * m11 + dx * dy * m12s + dy * dy * m22;
            dist = fminf(fmaxf(dist, 0.0f), 20.0f);
            const float wgt = __expf(-0.5f * dist) * qb[lidx];

            sumw += wgt;
            s0 += altb[lidx]             * wgt;
            s1 += altb[H * W + lidx]     * wgt;
            s2 += altb[2 * H * W + lidx] * wgt;
        }
    }

    const float inv = 1.0f / sumw;
    const size_t ob = (size_t)nn * CH * (SH * SW) + (size_t)y * SW + x;
    out[ob]                      = s0 * inv;
    out[ob + (size_t)(SH * SW)]  = s1 * inv;
    out[ob + (size_t)(2*SH*SW)]  = s2 * inv;
}

extern "C" void kernel_launch(void* const* d_in, const int* in_sizes, int n_in,
                              void* d_out, int out_size, void* d_ws, size_t ws_size,
                              hipStream_t stream) {
    const float* alts    = (const float*)d_in[0];
    const float* offsets = (const float*)d_in[1];
    const float* qs      = (const float*)d_in[2];
    const float* o11     = (const float*)d_in[3];
    const float* o12     = (const float*)d_in[4];
    const float* o21     = (const float*)d_in[5];
    const float* o22     = (const float*)d_in[6];
    float* out = (float*)d_out;

    const int total = NB * SH * SW;          // 1,048,576 threads
    const int block = 256;
    const int grid  = total / block;         // 4096
    superresolve_kernel<<<grid, block, 0, stream>>>(alts, offsets, qs,
                                                    o11, o12, o21, o22, out);
}

// Round 2
// 33.089 us; speedup vs baseline: 1.8225x; 1.8225x over previous
//
#include <hip/hip_runtime.h>

// SuperResolve: A=4 frames, n=4, c=3, h=w=256, S=2 -> out (4,3,512,512) fp32
// One thread per LOW-RES pixel (nn,y0,x0); computes the 2x2 output quad.
// All 36 (a,k) gathers are shared across the quad -> 4x fewer loads, coalesced.

#define SCALE   2
#define RADIUS  4.0f
#define AF      4      // alternate frames
#define NB      4      // batch
#define CH      3      // channels
#define H       256
#define W       256
#define SH      512
#define SW      512
#define HW      (H*W)
#define SHW     (SH*SW)

__global__ __launch_bounds__(256) void superresolve_kernel(
    const float* __restrict__ alts,     // [AF][NB][CH][H][W]
    const float* __restrict__ offsets,  // [AF][NB][2][H][W]
    const float* __restrict__ qs,       // [AF][NB][H][W]
    const float* __restrict__ o11,      // [NB][SH][SW]
    const float* __restrict__ o12,
    const float* __restrict__ o21,
    const float* __restrict__ o22,
    float* __restrict__ out)            // [NB][CH][SH][SW]
{
    // 1024 blocks total; bijective XCD swizzle (1024 % 8 == 0): each XCD gets
    // a contiguous band of rows -> low-res planes fetched ~once per XCD L2.
    const int bid = blockIdx.x;
    const int swz = (bid & 7) * (1024 / 8) + (bid >> 3);
    const int idx = swz * 256 + threadIdx.x;

    const int x0 = idx & (W - 1);
    const int y0 = (idx >> 8) & (H - 1);
    const int nn = idx >> 16;

    // Per-subpixel o-matrix (float2 loads, coalesced). s = sy*2 + sx.
    const int obase = (nn * SH + 2 * y0) * SW + 2 * x0;
    const float2 v11a = *(const float2*)(o11 + obase);
    const float2 v11b = *(const float2*)(o11 + obase + SW);
    const float2 v12a = *(const float2*)(o12 + obase);
    const float2 v12b = *(const float2*)(o12 + obase + SW);
    const float2 v21a = *(const float2*)(o21 + obase);
    const float2 v21b = *(const float2*)(o21 + obase + SW);
    const float2 v22a = *(const float2*)(o22 + obase);
    const float2 v22b = *(const float2*)(o22 + obase + SW);

    // fold the (1/S)^2 = 0.25 into the matrices
    float m11q[4], m12q[4], m22q[4];
    m11q[0] = 0.25f * v11a.x; m11q[1] = 0.25f * v11a.y;
    m11q[2] = 0.25f * v11b.x; m11q[3] = 0.25f * v11b.y;
    m12q[0] = 0.25f * (v12a.x + v21a.x); m12q[1] = 0.25f * (v12a.y + v21a.y);
    m12q[2] = 0.25f * (v12b.x + v21b.x); m12q[3] = 0.25f * (v12b.y + v21b.y);
    m22q[0] = 0.25f * v22a.x; m22q[1] = 0.25f * v22a.y;
    m22q[2] = 0.25f * v22b.x; m22q[3] = 0.25f * v22b.y;

    const float yf0 = (float)(2 * y0);
    const float xf0 = (float)(2 * x0);

    float sumw[4] = {0.f, 0.f, 0.f, 0.f};
    float acc0[4] = {0.f, 0.f, 0.f, 0.f};
    float acc1[4] = {0.f, 0.f, 0.f, 0.f};
    float acc2[4] = {0.f, 0.f, 0.f, 0.f};

    #pragma unroll
    for (int a = 0; a < AF; ++a) {
        const float* offb = offsets + (size_t)(a * NB + nn) * 2 * HW;
        const float* qb   = qs      + (size_t)(a * NB + nn) * HW;
        const float* altb = alts    + (size_t)(a * NB + nn) * CH * HW;
        #pragma unroll
        for (int k = 0; k < 9; ++k) {
            const int di = k / 3 - 1;
            const int dj = k % 3 - 1;
            const int rn = y0 + di;
            const int cn = x0 + dj;
            if (rn < 0 || rn >= H || cn < 0 || cn >= W) continue;  // inb mask
            const int lidx = rn * W + cn;

            const float offr = offb[lidx];
            const float offc = offb[HW + lidx];
            const float qv   = qb[lidx];
            const float a0   = altb[lidx];
            const float a1   = altb[HW + lidx];
            const float a2   = altb[2 * HW + lidx];

            const float posr = (float)(2 * rn) + 2.0f * offr;
            const float posc = (float)(2 * cn) + 2.0f * offc;

            // displacements for the two sub-rows / sub-cols
            const float dy0 = posr - yf0;
            const float dy1 = dy0 - 1.0f;
            const float dx0 = posc - xf0;
            const float dx1 = dx0 - 1.0f;

            #pragma unroll
            for (int s = 0; s < 4; ++s) {
                const float dyS = (s & 2) ? dy1 : dy0;
                const float dxS = (s & 1) ? dx1 : dx0;
                const bool valid = (fabsf(dyS) <= RADIUS) & (fabsf(dxS) <= RADIUS);
                float dist = dxS * dxS * m11q[s] + dxS * dyS * m12q[s]
                           + dyS * dyS * m22q[s];
                dist = fminf(fmaxf(dist, 0.0f), 20.0f);
                const float e = __expf(-0.5f * dist);
                const float wgt = valid ? e * qv : 0.0f;
                sumw[s] += wgt;
                acc0[s] = fmaf(a0, wgt, acc0[s]);
                acc1[s] = fmaf(a1, wgt, acc1[s]);
                acc2[s] = fmaf(a2, wgt, acc2[s]);
            }
        }
    }

    float inv[4];
    #pragma unroll
    for (int s = 0; s < 4; ++s) inv[s] = 1.0f / sumw[s];

    // coalesced float2 stores: 2 rows x 3 channels
    const size_t ob = (size_t)(nn * CH) * SHW + (size_t)(2 * y0) * SW + 2 * x0;
    *(float2*)(out + ob)                    = make_float2(acc0[0]*inv[0], acc0[1]*inv[1]);
    *(float2*)(out + ob + SW)               = make_float2(acc0[2]*inv[2], acc0[3]*inv[3]);
    *(float2*)(out + ob + SHW)              = make_float2(acc1[0]*inv[0], acc1[1]*inv[1]);
    *(float2*)(out + ob + SHW + SW)         = make_float2(acc1[2]*inv[2], acc1[3]*inv[3]);
    *(float2*)(out + ob + 2*SHW)            = make_float2(acc2[0]*inv[0], acc2[1]*inv[1]);
    *(float2*)(out + ob + 2*SHW + SW)       = make_float2(acc2[2]*inv[2], acc2[3]*inv[3]);
}

extern "C" void kernel_launch(void* const* d_in, const int* in_sizes, int n_in,
                              void* d_out, int out_size, void* d_ws, size_t ws_size,
                              hipStream_t stream) {
    const float* alts    = (const float*)d_in[0];
    const float* offsets = (const float*)d_in[1];
    const float* qs      = (const float*)d_in[2];
    const float* o11     = (const float*)d_in[3];
    const float* o12     = (const float*)d_in[4];
    const float* o21     = (const float*)d_in[5];
    const float* o22     = (const float*)d_in[6];
    float* out = (float*)d_out;

    const int total = NB * H * W;            // 262,144 threads (one per LR pixel)
    const int block = 256;
    const int grid  = total / block;         // 1024
    superresolve_kernel<<<grid, block, 0, stream>>>(alts, offsets, qs,
                                                    o11, o12, o21, o22, out);
}